// Round 5
// baseline (972.998 us; speedup 1.0000x reference)
//
#include <hip/hip_runtime.h>
#include <math.h>

#define N_TOK 8192
#define C_DIM 1024
#define D_DIM 3072
#define E_NUM 8
#define MAXB 72

typedef unsigned short u16;
typedef unsigned int u32;
typedef __attribute__((ext_vector_type(8))) short bf16x8;
typedef __attribute__((ext_vector_type(4))) float f32x4;

__device__ __forceinline__ u16 f2bf(float f) {
  u32 u = __builtin_bit_cast(unsigned int, f);
  u = (u + 0x7FFFu + ((u >> 16) & 1u)) >> 16;
  return (u16)u;
}

__device__ __forceinline__ void gl_lds16(const void* g, void* l) {
  __builtin_amdgcn_global_load_lds(
      (const __attribute__((address_space(1))) unsigned int*)g,
      (__attribute__((address_space(3))) unsigned int*)l, 16, 0, 0);
}

// fused counted-vmcnt wait + barrier (asm so the compiler can't drain vmcnt to 0)
template<int N> __device__ __forceinline__ void wait_bar() {
  if constexpr (N == 0)  asm volatile("s_waitcnt vmcnt(0)\n\ts_barrier" ::: "memory");
  else if constexpr (N == 3)  asm volatile("s_waitcnt vmcnt(3)\n\ts_barrier" ::: "memory");
  else if constexpr (N == 4)  asm volatile("s_waitcnt vmcnt(4)\n\ts_barrier" ::: "memory");
  else if constexpr (N == 6)  asm volatile("s_waitcnt vmcnt(6)\n\ts_barrier" ::: "memory");
  else if constexpr (N == 8)  asm volatile("s_waitcnt vmcnt(8)\n\ts_barrier" ::: "memory");
  else if constexpr (N == 9)  asm volatile("s_waitcnt vmcnt(9)\n\ts_barrier" ::: "memory");
  else if constexpr (N == 12) asm volatile("s_waitcnt vmcnt(12)\n\ts_barrier" ::: "memory");
}
__device__ __forceinline__ void bar_only() {
  asm volatile("s_barrier" ::: "memory");
}

// ---------------- init: zero output (incl aux loss) + counters ----------------
__global__ void zero_init_kernel(float* __restrict__ out, int n, int* __restrict__ cnt) {
  int i = blockIdx.x * 256 + threadIdx.x;
  if (i < n) out[i] = 0.0f;
  if (i < E_NUM) cnt[i] = 0;
}

// ---------------- W1 [E][C][D] f32 -> W1t [E][D][C] bf16 ----------------
__global__ void transpose_w1_kernel(const float* __restrict__ W1, u16* __restrict__ W1t) {
  __shared__ float t[32][33];
  const int e = blockIdx.z;
  const int d0 = blockIdx.x * 32, c0 = blockIdx.y * 32;
  const int tx = threadIdx.x, ty = threadIdx.y;
#pragma unroll
  for (int i = 0; i < 4; i++)
    t[ty + i * 8][tx] = W1[((size_t)e * C_DIM + c0 + ty + i * 8) * D_DIM + d0 + tx];
  __syncthreads();
#pragma unroll
  for (int i = 0; i < 4; i++)
    W1t[((size_t)e * D_DIM + d0 + ty + i * 8) * C_DIM + c0 + tx] = f2bf(t[tx][ty + i * 8]);
}

// ---------------- W2 [E][D][C] f32 -> W2t [E][C][D] bf16 ----------------
__global__ void transpose_w2_kernel(const float* __restrict__ W2, u16* __restrict__ W2t) {
  __shared__ float t[32][33];
  const int e = blockIdx.z;
  const int c0 = blockIdx.x * 32, d0 = blockIdx.y * 32;
  const int tx = threadIdx.x, ty = threadIdx.y;
#pragma unroll
  for (int i = 0; i < 4; i++)
    t[ty + i * 8][tx] = W2[((size_t)e * D_DIM + d0 + ty + i * 8) * C_DIM + c0 + tx];
  __syncthreads();
#pragma unroll
  for (int i = 0; i < 4; i++)
    W2t[((size_t)e * C_DIM + c0 + ty + i * 8) * D_DIM + d0 + tx] = f2bf(t[tx][ty + i * 8]);
}

// ---------------- router: logits (fp64), top-2, scatter ----------------
__global__ void router_kernel(const float* __restrict__ x, const float* __restrict__ rw,
                              int* __restrict__ cnt, int* __restrict__ list,
                              float* __restrict__ wl) {
  const int lane = threadIdx.x & 63;
  const int n = blockIdx.x * 4 + (threadIdx.x >> 6);
  const float* xr = x + (size_t)n * C_DIM;
  double acc[E_NUM];
#pragma unroll
  for (int e = 0; e < E_NUM; e++) acc[e] = 0.0;
  for (int c = lane; c < C_DIM; c += 64) {
    float xv = xr[c];
#pragma unroll
    for (int e = 0; e < E_NUM; e++) acc[e] += (double)xv * (double)rw[e * C_DIM + c];
  }
#pragma unroll
  for (int e = 0; e < E_NUM; e++) {
    double v = acc[e];
#pragma unroll
    for (int off = 32; off > 0; off >>= 1) v += __shfl_down(v, off, 64);
    acc[e] = v;
  }
  if (lane == 0) {
    int i0 = 0;
#pragma unroll
    for (int e = 1; e < E_NUM; e++) if (acc[e] > acc[i0]) i0 = e;
    int i1 = (i0 == 0) ? 1 : 0;
#pragma unroll
    for (int e = 0; e < E_NUM; e++) if (e != i0 && acc[e] > acc[i1]) i1 = e;
    double d = acc[i0] - acc[i1];          // >= 0
    double w0 = 1.0 / (1.0 + exp(-d));     // p0/(p0+p1)
    double w1 = 1.0 - w0;
    int p0 = atomicAdd(&cnt[i0], 1);
    list[i0 * N_TOK + p0] = n; wl[i0 * N_TOK + p0] = (float)w0;
    int p1 = atomicAdd(&cnt[i1], 1);
    list[i1 * N_TOK + p1] = n; wl[i1 * N_TOK + p1] = (float)w1;
  }
}

// ---------------- prefix sum + block table (BM=256 segments) ----------------
__global__ void prefix_kernel(const int* __restrict__ cnt, int* __restrict__ rowbase,
                              int* __restrict__ btab) {
  if (threadIdx.x == 0) {
    int s = 0, nb = 0;
    for (int e = 0; e < E_NUM; e++) {
      rowbase[e] = s;
      for (int m0 = 0; m0 < cnt[e]; m0 += 256) { btab[2 * nb] = e; btab[2 * nb + 1] = m0; nb++; }
      s += cnt[e];
    }
    for (; nb < MAXB; nb++) { btab[2 * nb] = -1; btab[2 * nb + 1] = 0; }
  }
}

// ---------------- gather + convert: Xg[rb+p] = bf16(x[list[e][p]]) ----------------
__global__ void gather_x_kernel(const float* __restrict__ x, const int* __restrict__ cnt,
                                const int* __restrict__ rowbase, const int* __restrict__ list,
                                u16* __restrict__ Xg) {
  const int e = blockIdx.y;
  const int p = blockIdx.x * 4 + (threadIdx.x >> 6);
  if (p >= cnt[e]) return;
  const int lane = threadIdx.x & 63;
  const int tok = list[e * N_TOK + p];
  const float* src = x + (size_t)tok * C_DIM;
  u16* dst = Xg + (size_t)(rowbase[e] + p) * C_DIM;
#pragma unroll
  for (int i = 0; i < 4; i++) {
    float4 v = *(const float4*)(src + lane * 4 + i * 256);
    ushort4 o;
    o.x = f2bf(v.x); o.y = f2bf(v.y); o.z = f2bf(v.z); o.w = f2bf(v.w);
    *(ushort4*)(dst + lane * 4 + i * 256) = o;
  }
}

// ------ 8-wave 256-row depth-3 GEMM, 2D-cohort XCD swizzle, optional split-K ------
// EPI=1: h = gelu(Xg @ W1t^T + b1)     A=Xg dense rows, Wt=[E][D][C]
// EPI=2: out += w*(h @ W2t^T + b2)     A=h dense rows,  Wt=[E][C][D], split-K x NKC
template<int BM, int BN, int NN0, int NKC, int KFULL, int EPI>
__global__ __launch_bounds__(512, 1) void gemm8p_kernel(
    const u16* __restrict__ A, const u16* __restrict__ Wt, const float* __restrict__ bias_,
    const int* __restrict__ btab, const int* __restrict__ cnt, const int* __restrict__ rowbase,
    const int* __restrict__ list, const float* __restrict__ wl,
    u16* __restrict__ hout, float* __restrict__ out) {
  constexpr int NTOT = NN0 * BN;    // 3072 / 1024
  constexpr int KC   = 1024;        // K-chunk per block
  constexpr int NH   = KC / 32;     // 32 half-tiles
  constexpr int TM = BM / 2;        // 128 (2 M-waves)
  constexpr int TN = BN / 4;        // 64 / 32 (4 N-waves)
  constexpr int MR = TM / 16;       // 8
  constexpr int NR = TN / 16;       // 4 / 2
  constexpr int RA = BM / 128;      // gl_lds reps A = 2
  constexpr int RB = BN / 128;      // 2 / 1
  constexpr int VS = RA + RB;       // vmcnt per stage
  constexpr int TOTB = MAXB * NN0 * NKC;
  constexpr int QPK  = (MAXB / 4) * (NN0 / 4);   // cohorts per k-chunk

  __shared__ __align__(16) u16 ldsA[4 * BM * 32];  // 4 half-tile slots
  __shared__ __align__(16) u16 ldsB[4 * BN * 32];

  // T1 bijective chunked XCD swizzle + 4bx x 4n0 cohort decode (L2 residency)
  const int Lp = (blockIdx.x & 7) * (TOTB / 8) + (blockIdx.x >> 3);
  const int q = Lp >> 4, r = Lp & 15;
  const int kc = q / QPK;
  const int qq = q - kc * QPK;
  const int bxg = qq / (NN0 / 4), n0g = qq % (NN0 / 4);
  const int bx = bxg * 4 + (r >> 2);
  const int n0 = (n0g * 4 + (r & 3)) * BN;

  const int e = btab[bx * 2];
  if (e < 0) return;
  const int m0 = btab[bx * 2 + 1];
  const int count = cnt[e];
  const int rb = rowbase[e];

  const int tid = threadIdx.x;
  const int lane = tid & 63;
  const int wid = tid >> 6;
  const int wr = wid >> 2, wc = wid & 3;
  const int l15 = lane & 15, l4 = lane >> 4;

  // staging: thread handles 16B chunk c = tid + r*512; row=c>>2, pos=c&3.
  // T2 swizzle (involution): source chunk = pos ^ ((row>>1)&3); LDS dest linear.
  const int cs8 = ((tid & 3) ^ ((tid >> 3) & 3)) * 8;
  const u16* aptrs[RA];
#pragma unroll
  for (int rr = 0; rr < RA; rr++) {
    const int arow = (tid + rr * 512) >> 2;
    const int mm = min(m0 + arow, count - 1);
    aptrs[rr] = A + (size_t)(rb + mm) * KFULL + kc * KC + cs8;
  }
  const u16* bptrs[RB];
#pragma unroll
  for (int rr = 0; rr < RB; rr++) {
    const int brow = (tid + rr * 512) >> 2;
    bptrs[rr] = Wt + ((size_t)e * NTOT + n0 + brow) * KFULL + kc * KC + cs8;
  }

  // fragment read offsets (swizzled): row*32 + (chunk ^ ((row>>1)&3))*8
  const int swz = (l15 >> 1) & 3;
  const int paoff = (wr * TM + l15) * 32 + ((l4 ^ swz) * 8);
  const int pboff = (wc * TN + l15) * 32 + ((l4 ^ swz) * 8);

  f32x4 acc[MR][NR];
#pragma unroll
  for (int i = 0; i < MR; i++)
#pragma unroll
    for (int j = 0; j < NR; j++) acc[i][j] = {0.f, 0.f, 0.f, 0.f};

  auto STAGE = [&](int h) {   // stage half-tile h into slot h&3
    u16* da = ldsA + (h & 3) * (BM * 32) + tid * 8;
    u16* db = ldsB + (h & 3) * (BN * 32) + tid * 8;
    const int ko = h * 32;
#pragma unroll
    for (int rr = 0; rr < RA; rr++) gl_lds16(aptrs[rr] + ko, da + rr * 4096);
#pragma unroll
    for (int rr = 0; rr < RB; rr++) gl_lds16(bptrs[rr] + ko, db + rr * 4096);
  };

  auto PHASE = [&](int h) {
    const u16* pa = ldsA + (h & 3) * (BM * 32) + paoff;
    const u16* pb = ldsB + (h & 3) * (BN * 32) + pboff;
    bf16x8 av[MR], bv[NR];
#pragma unroll
    for (int i = 0; i < MR; i++) av[i] = *(const bf16x8*)(pa + i * 512);
#pragma unroll
    for (int j = 0; j < NR; j++) bv[j] = *(const bf16x8*)(pb + j * 512);
    __builtin_amdgcn_s_setprio(1);
#pragma unroll
    for (int i = 0; i < MR; i++)
#pragma unroll
      for (int j = 0; j < NR; j++)
        acc[i][j] = __builtin_amdgcn_mfma_f32_16x16x32_bf16(av[i], bv[j], acc[i][j], 0, 0, 0);
    __builtin_amdgcn_s_setprio(0);
  };

  // prologue: 3 half-tiles in flight (T4: counted vmcnt, never 0 in main loop)
  STAGE(0); STAGE(1); STAGE(2);
  for (int h = 0; h < NH - 3; ++h) {
    STAGE(h + 3);         // slot (h+3)&3 == (h-1)&3, released by prev iter's end-barrier
    wait_bar<3 * VS>();   // half-tile h landed (h+1..h+3 may fly)
    PHASE(h);
    bar_only();           // release slot h for overwrite next iteration
  }
  wait_bar<2 * VS>(); PHASE(NH - 3); bar_only();
  wait_bar<VS>();     PHASE(NH - 2); bar_only();
  wait_bar<0>();      PHASE(NH - 1);

  // ---------------- epilogue ----------------
  if constexpr (EPI == 1) {
#pragma unroll
    for (int i = 0; i < MR; i++) {
      const int rloc = wr * TM + i * 16 + l4 * 4;
#pragma unroll
      for (int j = 0; j < NR; j++) {
        const int col = n0 + wc * TN + j * 16 + l15;
        const float bias = bias_[e * NTOT + col];
#pragma unroll
        for (int rr = 0; rr < 4; rr++) {
          const int m = m0 + rloc + rr;
          if (m < count) {
            float v = acc[i][j][rr] + bias;
            float g = 0.5f * v * (1.0f + erff(v * 0.70710678118654752f));
            hout[(size_t)(rb + m) * D_DIM + col] = f2bf(g);
          }
        }
      }
    }
  } else {
    const int* lst = list + e * N_TOK;
    const float* wlst = wl + e * N_TOK;
#pragma unroll
    for (int i = 0; i < MR; i++) {
      const int rloc = wr * TM + i * 16 + l4 * 4;
#pragma unroll
      for (int j = 0; j < NR; j++) {
        const int col = n0 + wc * TN + j * 16 + l15;
        const float bias = (kc == 0) ? bias_[e * NTOT + col] : 0.0f;
#pragma unroll
        for (int rr = 0; rr < 4; rr++) {
          const int m = m0 + rloc + rr;
          if (m < count) {
            const int tk = lst[m];
            atomicAdd(out + (size_t)tk * C_DIM + col, wlst[m] * (acc[i][j][rr] + bias));
          }
        }
      }
    }
  }
}

extern "C" void kernel_launch(void* const* d_in, const int* in_sizes, int n_in,
                              void* d_out, int out_size, void* d_ws, size_t ws_size,
                              hipStream_t stream) {
  const float* x  = (const float*)d_in[0];
  const float* rw = (const float*)d_in[1];
  const float* W1 = (const float*)d_in[2];
  const float* b1 = (const float*)d_in[3];
  const float* W2 = (const float*)d_in[4];
  const float* b2 = (const float*)d_in[5];
  float* out = (float*)d_out;

  char* ws = (char*)d_ws;
  u16* W1t    = (u16*)(ws);                      // 50,331,648 B
  u16* Xg     = (u16*)(ws + 50331648);           // 33,554,432 B (later overlaid by W2t)
  u16* W2t    = (u16*)(ws + 50331648);           // 50,331,648 B (written AFTER gemm1)
  int* cnt    = (int*)(ws + 100663296);          // 256 B
  int* rowbase= (int*)(ws + 100663552);          // 256 B
  int* list   = (int*)(ws + 100663808);          // 262,144 B
  float* wl   = (float*)(ws + 100925952);        // 262,144 B
  int* btab   = (int*)(ws + 101188096);          // 1,024 B
  u16* h      = (u16*)(ws + 101189632);          // 100,663,296 B -> end 201,852,928

  zero_init_kernel<<<(out_size + 255) / 256, 256, 0, stream>>>(out, out_size, cnt);
  router_kernel<<<N_TOK / 4, 256, 0, stream>>>(x, rw, cnt, list, wl);
  prefix_kernel<<<1, 64, 0, stream>>>(cnt, rowbase, btab);
  gather_x_kernel<<<dim3(N_TOK / 4, E_NUM), 256, 0, stream>>>(x, cnt, rowbase, list, Xg);
  transpose_w1_kernel<<<dim3(D_DIM / 32, C_DIM / 32, E_NUM), dim3(32, 8), 0, stream>>>(W1, W1t);
  gemm8p_kernel<256, 256, 12, 1, C_DIM, 1><<<MAXB * 12, 512, 0, stream>>>(
      Xg, W1t, b1, btab, cnt, rowbase, list, wl, h, out);
  transpose_w2_kernel<<<dim3(C_DIM / 32, D_DIM / 32, E_NUM), dim3(32, 8), 0, stream>>>(W2, W2t);
  gemm8p_kernel<256, 128, 8, 3, D_DIM, 2><<<MAXB * 8 * 3, 512, 0, stream>>>(
      h, W2t, b2, btab, cnt, rowbase, list, wl, h, out);
}

// Round 6
// 689.299 us; speedup vs baseline: 1.4116x; 1.4116x over previous
//
#include <hip/hip_runtime.h>
#include <math.h>

#define N_TOK 8192
#define C_DIM 1024
#define D_DIM 3072
#define E_NUM 8
#define SEG 128
#define MAXB 136   // sum ceil(cnt_e/128) <= 128 + 8

typedef unsigned short u16;
typedef unsigned int u32;
typedef __attribute__((ext_vector_type(8))) short bf16x8;
typedef __attribute__((ext_vector_type(4))) float f32x4;

__device__ __forceinline__ u16 f2bf(float f) {
  u32 u = __builtin_bit_cast(unsigned int, f);
  u = (u + 0x7FFFu + ((u >> 16) & 1u)) >> 16;
  return (u16)u;
}

__device__ __forceinline__ void gl_lds16(const void* g, void* l) {
  __builtin_amdgcn_global_load_lds(
      (const __attribute__((address_space(1))) unsigned int*)g,
      (__attribute__((address_space(3))) unsigned int*)l, 16, 0, 0);
}

// fused counted-vmcnt wait + barrier (asm so the compiler can't drain vmcnt to 0)
template<int N> __device__ __forceinline__ void wait_bar() {
  if constexpr (N == 0) asm volatile("s_waitcnt vmcnt(0)\n\ts_barrier" ::: "memory");
  else if constexpr (N == 4) asm volatile("s_waitcnt vmcnt(4)\n\ts_barrier" ::: "memory");
}
__device__ __forceinline__ void bar_only() {
  asm volatile("s_barrier" ::: "memory");
}

// ---------------- init: zero output (incl aux loss) + counters ----------------
__global__ void zero_init_kernel(float* __restrict__ out, int n, int* __restrict__ cnt) {
  int i = blockIdx.x * 256 + threadIdx.x;
  if (i < n) out[i] = 0.0f;
  if (i < E_NUM) cnt[i] = 0;
}

// ---------------- W1 [E][C][D] f32 -> W1t [E][D][C] bf16 ----------------
__global__ void transpose_w1_kernel(const float* __restrict__ W1, u16* __restrict__ W1t) {
  __shared__ float t[32][33];
  const int e = blockIdx.z;
  const int d0 = blockIdx.x * 32, c0 = blockIdx.y * 32;
  const int tx = threadIdx.x, ty = threadIdx.y;
#pragma unroll
  for (int i = 0; i < 4; i++)
    t[ty + i * 8][tx] = W1[((size_t)e * C_DIM + c0 + ty + i * 8) * D_DIM + d0 + tx];
  __syncthreads();
#pragma unroll
  for (int i = 0; i < 4; i++)
    W1t[((size_t)e * D_DIM + d0 + ty + i * 8) * C_DIM + c0 + tx] = f2bf(t[tx][ty + i * 8]);
}

// ---------------- W2 [E][D][C] f32 -> W2t [E][C][D] bf16 ----------------
__global__ void transpose_w2_kernel(const float* __restrict__ W2, u16* __restrict__ W2t) {
  __shared__ float t[32][33];
  const int e = blockIdx.z;
  const int c0 = blockIdx.x * 32, d0 = blockIdx.y * 32;
  const int tx = threadIdx.x, ty = threadIdx.y;
#pragma unroll
  for (int i = 0; i < 4; i++)
    t[ty + i * 8][tx] = W2[((size_t)e * D_DIM + d0 + ty + i * 8) * C_DIM + c0 + tx];
  __syncthreads();
#pragma unroll
  for (int i = 0; i < 4; i++)
    W2t[((size_t)e * C_DIM + c0 + ty + i * 8) * D_DIM + d0 + tx] = f2bf(t[tx][ty + i * 8]);
}

// ---------------- router: logits (fp64), top-2, scatter ----------------
__global__ void router_kernel(const float* __restrict__ x, const float* __restrict__ rw,
                              int* __restrict__ cnt, int* __restrict__ list,
                              float* __restrict__ wl) {
  const int lane = threadIdx.x & 63;
  const int n = blockIdx.x * 4 + (threadIdx.x >> 6);
  const float* xr = x + (size_t)n * C_DIM;
  double acc[E_NUM];
#pragma unroll
  for (int e = 0; e < E_NUM; e++) acc[e] = 0.0;
  for (int c = lane; c < C_DIM; c += 64) {
    float xv = xr[c];
#pragma unroll
    for (int e = 0; e < E_NUM; e++) acc[e] += (double)xv * (double)rw[e * C_DIM + c];
  }
#pragma unroll
  for (int e = 0; e < E_NUM; e++) {
    double v = acc[e];
#pragma unroll
    for (int off = 32; off > 0; off >>= 1) v += __shfl_down(v, off, 64);
    acc[e] = v;
  }
  if (lane == 0) {
    int i0 = 0;
#pragma unroll
    for (int e = 1; e < E_NUM; e++) if (acc[e] > acc[i0]) i0 = e;
    int i1 = (i0 == 0) ? 1 : 0;
#pragma unroll
    for (int e = 0; e < E_NUM; e++) if (e != i0 && acc[e] > acc[i1]) i1 = e;
    double d = acc[i0] - acc[i1];          // >= 0
    double w0 = 1.0 / (1.0 + exp(-d));     // p0/(p0+p1)
    double w1 = 1.0 - w0;
    int p0 = atomicAdd(&cnt[i0], 1);
    list[i0 * N_TOK + p0] = n; wl[i0 * N_TOK + p0] = (float)w0;
    int p1 = atomicAdd(&cnt[i1], 1);
    list[i1 * N_TOK + p1] = n; wl[i1 * N_TOK + p1] = (float)w1;
  }
}

// ---------------- prefix sum + block table (SEG-row segments) ----------------
__global__ void prefix_kernel(const int* __restrict__ cnt, int* __restrict__ rowbase,
                              int* __restrict__ btab) {
  if (threadIdx.x == 0) {
    int s = 0, nb = 0;
    for (int e = 0; e < E_NUM; e++) {
      rowbase[e] = s;
      for (int m0 = 0; m0 < cnt[e]; m0 += SEG) { btab[2 * nb] = e; btab[2 * nb + 1] = m0; nb++; }
      s += cnt[e];
    }
    for (; nb < MAXB; nb++) { btab[2 * nb] = -1; btab[2 * nb + 1] = 0; }
  }
}

// ---------------- gather + convert: Xg[rb+p] = bf16(x[list[e][p]]) ----------------
__global__ void gather_x_kernel(const float* __restrict__ x, const int* __restrict__ cnt,
                                const int* __restrict__ rowbase, const int* __restrict__ list,
                                u16* __restrict__ Xg) {
  const int e = blockIdx.y;
  const int p = blockIdx.x * 4 + (threadIdx.x >> 6);
  if (p >= cnt[e]) return;
  const int lane = threadIdx.x & 63;
  const int tok = list[e * N_TOK + p];
  const float* src = x + (size_t)tok * C_DIM;
  u16* dst = Xg + (size_t)(rowbase[e] + p) * C_DIM;
#pragma unroll
  for (int i = 0; i < 4; i++) {
    float4 v = *(const float4*)(src + lane * 4 + i * 256);
    ushort4 o;
    o.x = f2bf(v.x); o.y = f2bf(v.y); o.z = f2bf(v.z); o.w = f2bf(v.w);
    *(ushort4*)(dst + lane * 4 + i * 256) = o;
  }
}

// ------- 128x128 tile, 256 threads, 32KB LDS dbuf, 4 blocks/CU (TLP) -------
// EPI=1: h = gelu(Xg @ W1t^T + b1)     A=Xg dense rows, Wt=[E][D][C]
// EPI=2: out += w*(h @ W2t^T + b2)     A=h dense rows,  Wt=[E][C][D]
template<int NN0, int K, int EPI>
__global__ __launch_bounds__(256, 4) void gemm_tlp_kernel(
    const u16* __restrict__ A, const u16* __restrict__ Wt, const float* __restrict__ bias_,
    const int* __restrict__ btab, const int* __restrict__ cnt, const int* __restrict__ rowbase,
    const int* __restrict__ list, const float* __restrict__ wl,
    u16* __restrict__ hout, float* __restrict__ out) {
  constexpr int NTOT = NN0 * 128;
  constexpr int NT = K / 32;       // K-steps
  constexpr int TOT = MAXB * NN0;  // grid size (TOT % 8 == 0)

  __shared__ __align__(16) u16 ldsA[2 * 128 * 32];  // 16 KB
  __shared__ __align__(16) u16 ldsB[2 * 128 * 32];  // 16 KB

  // bijective XCD chunking; n0-minor order: co-resident blocks share A-panels
  const int L = (blockIdx.x & 7) * (TOT / 8) + (blockIdx.x >> 3);
  const int bx = L / NN0;
  const int n0 = (L % NN0) * 128;

  const int e = btab[bx * 2];
  if (e < 0) return;
  const int m0 = btab[bx * 2 + 1];
  const int count = cnt[e];
  const int rb = rowbase[e];

  const int tid = threadIdx.x;
  const int lane = tid & 63;
  const int wid = tid >> 6;
  const int wm = (wid >> 1) * 64;
  const int wn = (wid & 1) * 64;
  const int l15 = lane & 15, l4 = lane >> 4;

  // staging: chunk c = tid + r*256; row = c>>2; 16B pos = (c&3)*8 u16. LINEAR (coalesced).
  const int arow0 = tid >> 2, pos = (tid & 3) * 8;
  const u16* aptr0 = A + (size_t)(rb + min(m0 + arow0, count - 1)) * K + pos;
  const u16* aptr1 = A + (size_t)(rb + min(m0 + arow0 + 64, count - 1)) * K + pos;
  const u16* bptr0 = Wt + ((size_t)e * NTOT + n0 + arow0) * K + pos;
  const u16* bptr1 = Wt + ((size_t)e * NTOT + n0 + arow0 + 64) * K + pos;

  const int paoff = (wm + l15) * 32 + l4 * 8;
  const int pboff = (wn + l15) * 32 + l4 * 8;

  f32x4 acc[4][4];
#pragma unroll
  for (int i = 0; i < 4; i++)
#pragma unroll
    for (int j = 0; j < 4; j++) acc[i][j] = {0.f, 0.f, 0.f, 0.f};

  auto STAGE = [&](int t, int b) {
    u16* da = ldsA + b * 4096 + tid * 8;
    u16* db = ldsB + b * 4096 + tid * 8;
    const int ko = t * 32;
    gl_lds16(aptr0 + ko, da);
    gl_lds16(aptr1 + ko, da + 2048);
    gl_lds16(bptr0 + ko, db);
    gl_lds16(bptr1 + ko, db + 2048);
  };

  auto PHASE = [&](int b) {
    const u16* pa = ldsA + b * 4096 + paoff;
    const u16* pb = ldsB + b * 4096 + pboff;
    bf16x8 av[4], bv[4];
#pragma unroll
    for (int i = 0; i < 4; i++) av[i] = *(const bf16x8*)(pa + i * 512);
#pragma unroll
    for (int j = 0; j < 4; j++) bv[j] = *(const bf16x8*)(pb + j * 512);
#pragma unroll
    for (int i = 0; i < 4; i++)
#pragma unroll
      for (int j = 0; j < 4; j++)
        acc[i][j] = __builtin_amdgcn_mfma_f32_16x16x32_bf16(av[i], bv[j], acc[i][j], 0, 0, 0);
  };

  // double-buffer, counted vmcnt: prefetch of t+1 stays in flight across the barrier
  STAGE(0, 0);
#pragma unroll 2
  for (int t = 0; t < NT - 1; ++t) {
    STAGE(t + 1, (t + 1) & 1);
    wait_bar<4>();            // t's 4 loads landed; t+1's may fly
    PHASE(t & 1);
    bar_only();               // all waves done reading buf t&1 before overwrite
  }
  wait_bar<0>();
  PHASE((NT - 1) & 1);

  // ---------------- epilogue ----------------
  if constexpr (EPI == 1) {
#pragma unroll
    for (int i = 0; i < 4; i++) {
      const int rloc = wm + i * 16 + l4 * 4;
#pragma unroll
      for (int j = 0; j < 4; j++) {
        const int col = n0 + wn + j * 16 + l15;
        const float bias = bias_[e * NTOT + col];
#pragma unroll
        for (int r = 0; r < 4; r++) {
          const int m = m0 + rloc + r;
          if (m < count) {
            float v = acc[i][j][r] + bias;
            float g = 0.5f * v * (1.0f + erff(v * 0.70710678118654752f));
            hout[(size_t)(rb + m) * D_DIM + col] = f2bf(g);
          }
        }
      }
    }
  } else {
    const int* lst = list + e * N_TOK;
    const float* wlst = wl + e * N_TOK;
#pragma unroll
    for (int i = 0; i < 4; i++) {
      const int rloc = wm + i * 16 + l4 * 4;
#pragma unroll
      for (int j = 0; j < 4; j++) {
        const int col = n0 + wn + j * 16 + l15;
        const float bias = bias_[e * NTOT + col];
#pragma unroll
        for (int r = 0; r < 4; r++) {
          const int m = m0 + rloc + r;
          if (m < count) {
            const int tk = lst[m];
            atomicAdd(out + (size_t)tk * C_DIM + col, wlst[m] * (acc[i][j][r] + bias));
          }
        }
      }
    }
  }
}

extern "C" void kernel_launch(void* const* d_in, const int* in_sizes, int n_in,
                              void* d_out, int out_size, void* d_ws, size_t ws_size,
                              hipStream_t stream) {
  const float* x  = (const float*)d_in[0];
  const float* rw = (const float*)d_in[1];
  const float* W1 = (const float*)d_in[2];
  const float* b1 = (const float*)d_in[3];
  const float* W2 = (const float*)d_in[4];
  const float* b2 = (const float*)d_in[5];
  float* out = (float*)d_out;

  char* ws = (char*)d_ws;
  u16* W1t    = (u16*)(ws);                      // 50,331,648 B
  u16* Xg     = (u16*)(ws + 50331648);           // 33,554,432 B (overlaid by W2t after gemm1)
  u16* W2t    = (u16*)(ws + 50331648);           // 50,331,648 B (written AFTER gemm1)
  int* cnt    = (int*)(ws + 100663296);          // 256 B
  int* rowbase= (int*)(ws + 100663552);          // 256 B
  int* list   = (int*)(ws + 100663808);          // 262,144 B
  float* wl   = (float*)(ws + 100925952);        // 262,144 B
  int* btab   = (int*)(ws + 101188096);          // 2,048 B
  u16* h      = (u16*)(ws + 101190656);          // 100,663,296 B -> end 201,853,952

  zero_init_kernel<<<(out_size + 255) / 256, 256, 0, stream>>>(out, out_size, cnt);
  router_kernel<<<N_TOK / 4, 256, 0, stream>>>(x, rw, cnt, list, wl);
  prefix_kernel<<<1, 64, 0, stream>>>(cnt, rowbase, btab);
  gather_x_kernel<<<dim3(N_TOK / 4, E_NUM), 256, 0, stream>>>(x, cnt, rowbase, list, Xg);
  transpose_w1_kernel<<<dim3(D_DIM / 32, C_DIM / 32, E_NUM), dim3(32, 8), 0, stream>>>(W1, W1t);
  gemm_tlp_kernel<24, C_DIM, 1><<<MAXB * 24, 256, 0, stream>>>(
      Xg, W1t, b1, btab, cnt, rowbase, list, wl, h, out);
  transpose_w2_kernel<<<dim3(C_DIM / 32, D_DIM / 32, E_NUM), dim3(32, 8), 0, stream>>>(W2, W2t);
  gemm_tlp_kernel<8, D_DIM, 2><<<MAXB * 8, 256, 0, stream>>>(
      h, W2t, b2, btab, cnt, rowbase, list, wl, h, out);
}

// Round 7
// 671.455 us; speedup vs baseline: 1.4491x; 1.0266x over previous
//
#include <hip/hip_runtime.h>
#include <math.h>

#define N_TOK 8192
#define C_DIM 1024
#define D_DIM 3072
#define E_NUM 8
#define SEG 128
#define MAXB 136   // sum ceil(cnt_e/128) <= 128 + 8; MAXB % 4 == 0

typedef unsigned short u16;
typedef unsigned int u32;
typedef __attribute__((ext_vector_type(8))) short bf16x8;
typedef __attribute__((ext_vector_type(4))) float f32x4;

__device__ __forceinline__ u16 f2bf(float f) {
  u32 u = __builtin_bit_cast(unsigned int, f);
  u = (u + 0x7FFFu + ((u >> 16) & 1u)) >> 16;
  return (u16)u;
}

__device__ __forceinline__ void gl_lds16(const void* g, void* l) {
  __builtin_amdgcn_global_load_lds(
      (const __attribute__((address_space(1))) unsigned int*)g,
      (__attribute__((address_space(3))) unsigned int*)l, 16, 0, 0);
}

// fused counted-vmcnt wait + barrier (asm so the compiler can't drain vmcnt to 0)
template<int N> __device__ __forceinline__ void wait_bar() {
  if constexpr (N == 0) asm volatile("s_waitcnt vmcnt(0)\n\ts_barrier" ::: "memory");
  else if constexpr (N == 4) asm volatile("s_waitcnt vmcnt(4)\n\ts_barrier" ::: "memory");
}
__device__ __forceinline__ void bar_only() {
  asm volatile("s_barrier" ::: "memory");
}

// ---------------- init: zero output (incl aux loss) + counters ----------------
__global__ void zero_init_kernel(float* __restrict__ out, int n, int* __restrict__ cnt) {
  int i = blockIdx.x * 256 + threadIdx.x;
  if (i < n) out[i] = 0.0f;
  if (i < E_NUM) cnt[i] = 0;
}

// -------- transpose+convert: in [E][R][CC] f32 -> out [E][CC][R] bf16 --------
// 64x64 tiles, float4 coalesced loads, ushort8 coalesced stores.
template<int R, int CC>
__global__ __launch_bounds__(256) void transpose_conv_kernel(
    const float* __restrict__ in, u16* __restrict__ outp) {
  __shared__ float t[64][65];
  const int e = blockIdx.z;
  const int r0 = blockIdx.y * 64;   // input-row tile base
  const int c0 = blockIdx.x * 64;   // input-col tile base
  const int tid = threadIdx.x;
  const int lr = tid >> 4;          // 0..15
  const int lc = (tid & 15) * 4;    // 0..60
#pragma unroll
  for (int i = 0; i < 4; i++) {
    float4 v = *(const float4*)(in + ((size_t)e * R + r0 + lr + i * 16) * CC + c0 + lc);
    t[lr + i * 16][lc] = v.x; t[lr + i * 16][lc + 1] = v.y;
    t[lr + i * 16][lc + 2] = v.z; t[lr + i * 16][lc + 3] = v.w;
  }
  __syncthreads();
  const int orow = tid >> 3;        // 0..31
  const int oc = (tid & 7) * 8;     // 0..56
#pragma unroll
  for (int i = 0; i < 2; i++) {
    const int d = orow + i * 32;    // output row = input col c0+d
    union { u16 s[8]; uint4 v; } o;
#pragma unroll
    for (int j = 0; j < 8; j++) o.s[j] = f2bf(t[oc + j][d]);
    *(uint4*)(outp + ((size_t)e * CC + c0 + d) * R + r0 + oc) = o.v;
  }
}

// ---------------- router: logits (fp64), top-2, scatter ----------------
__global__ void router_kernel(const float* __restrict__ x, const float* __restrict__ rw,
                              int* __restrict__ cnt, int* __restrict__ list,
                              float* __restrict__ wl) {
  const int lane = threadIdx.x & 63;
  const int n = blockIdx.x * 4 + (threadIdx.x >> 6);
  const float* xr = x + (size_t)n * C_DIM;
  double acc[E_NUM];
#pragma unroll
  for (int e = 0; e < E_NUM; e++) acc[e] = 0.0;
  for (int c = lane; c < C_DIM; c += 64) {
    float xv = xr[c];
#pragma unroll
    for (int e = 0; e < E_NUM; e++) acc[e] += (double)xv * (double)rw[e * C_DIM + c];
  }
#pragma unroll
  for (int e = 0; e < E_NUM; e++) {
    double v = acc[e];
#pragma unroll
    for (int off = 32; off > 0; off >>= 1) v += __shfl_down(v, off, 64);
    acc[e] = v;
  }
  if (lane == 0) {
    int i0 = 0;
#pragma unroll
    for (int e = 1; e < E_NUM; e++) if (acc[e] > acc[i0]) i0 = e;
    int i1 = (i0 == 0) ? 1 : 0;
#pragma unroll
    for (int e = 0; e < E_NUM; e++) if (e != i0 && acc[e] > acc[i1]) i1 = e;
    double d = acc[i0] - acc[i1];          // >= 0
    double w0 = 1.0 / (1.0 + exp(-d));     // p0/(p0+p1)
    double w1 = 1.0 - w0;
    int p0 = atomicAdd(&cnt[i0], 1);
    list[i0 * N_TOK + p0] = n; wl[i0 * N_TOK + p0] = (float)w0;
    int p1 = atomicAdd(&cnt[i1], 1);
    list[i1 * N_TOK + p1] = n; wl[i1 * N_TOK + p1] = (float)w1;
  }
}

// ---------------- prefix sum + block table (SEG-row segments) ----------------
__global__ void prefix_kernel(const int* __restrict__ cnt, int* __restrict__ rowbase,
                              int* __restrict__ btab) {
  if (threadIdx.x == 0) {
    int s = 0, nb = 0;
    for (int e = 0; e < E_NUM; e++) {
      rowbase[e] = s;
      for (int m0 = 0; m0 < cnt[e]; m0 += SEG) { btab[2 * nb] = e; btab[2 * nb + 1] = m0; nb++; }
      s += cnt[e];
    }
    for (; nb < MAXB; nb++) { btab[2 * nb] = -1; btab[2 * nb + 1] = 0; }
  }
}

// ---------------- gather + convert: Xg[rb+p] = bf16(x[list[e][p]]) ----------------
__global__ void gather_x_kernel(const float* __restrict__ x, const int* __restrict__ cnt,
                                const int* __restrict__ rowbase, const int* __restrict__ list,
                                u16* __restrict__ Xg) {
  const int e = blockIdx.y;
  const int p = blockIdx.x * 4 + (threadIdx.x >> 6);
  if (p >= cnt[e]) return;
  const int lane = threadIdx.x & 63;
  const int tok = list[e * N_TOK + p];
  const float* src = x + (size_t)tok * C_DIM;
  u16* dst = Xg + (size_t)(rowbase[e] + p) * C_DIM;
#pragma unroll
  for (int i = 0; i < 4; i++) {
    float4 v = *(const float4*)(src + lane * 4 + i * 256);
    ushort4 o;
    o.x = f2bf(v.x); o.y = f2bf(v.y); o.z = f2bf(v.z); o.w = f2bf(v.w);
    *(ushort4*)(dst + lane * 4 + i * 256) = o;
  }
}

// ------- 128x128 tile, 256 threads, 32KB LDS dbuf, 4 blocks/CU (TLP) -------
// Cohort dispatch: 4bx x 4n0 cohorts per XCD chunk -> L2-resident panels,
// ~4x less L3 read traffic. n0g-minor across cohorts keeps A hot across cohorts.
// EPI=1: h = gelu(Xg @ W1t^T + b1)     A=Xg dense rows, Wt=[E][D][C]
// EPI=2: out += w*(h @ W2t^T + b2)     A=h dense rows,  Wt=[E][C][D]
template<int NN0, int K, int EPI>
__global__ __launch_bounds__(256, 4) void gemm_tlp_kernel(
    const u16* __restrict__ A, const u16* __restrict__ Wt, const float* __restrict__ bias_,
    const int* __restrict__ btab, const int* __restrict__ cnt, const int* __restrict__ rowbase,
    const int* __restrict__ list, const float* __restrict__ wl,
    u16* __restrict__ hout, float* __restrict__ out) {
  constexpr int NTOT = NN0 * 128;
  constexpr int NT = K / 32;       // K-steps
  constexpr int NG = NN0 / 4;      // n0 cohort groups
  constexpr int TOT = MAXB * NN0;  // grid size (TOT % 8 == 0)

  __shared__ __align__(16) u16 ldsA[2 * 128 * 32];  // 16 KB
  __shared__ __align__(16) u16 ldsB[2 * 128 * 32];  // 16 KB

  // bijective XCD chunking, then 4x4 cohort decode
  const int L = (blockIdx.x & 7) * (TOT / 8) + (blockIdx.x >> 3);
  const int coh = L >> 4, r = L & 15;
  const int bxg = coh / NG;
  const int n0g = coh % NG;
  const int bx = bxg * 4 + (r & 3);
  const int n0 = (n0g * 4 + (r >> 2)) * 128;

  const int e = btab[bx * 2];
  if (e < 0) return;
  const int m0 = btab[bx * 2 + 1];
  const int count = cnt[e];
  const int rb = rowbase[e];

  const int tid = threadIdx.x;
  const int lane = tid & 63;
  const int wid = tid >> 6;
  const int wm = (wid >> 1) * 64;
  const int wn = (wid & 1) * 64;
  const int l15 = lane & 15, l4 = lane >> 4;

  // staging: chunk c = tid + r*256; row = c>>2; 16B pos = (c&3)*8 u16. LINEAR (coalesced).
  const int arow0 = tid >> 2, pos = (tid & 3) * 8;
  const u16* aptr0 = A + (size_t)(rb + min(m0 + arow0, count - 1)) * K + pos;
  const u16* aptr1 = A + (size_t)(rb + min(m0 + arow0 + 64, count - 1)) * K + pos;
  const u16* bptr0 = Wt + ((size_t)e * NTOT + n0 + arow0) * K + pos;
  const u16* bptr1 = Wt + ((size_t)e * NTOT + n0 + arow0 + 64) * K + pos;

  const int paoff = (wm + l15) * 32 + l4 * 8;
  const int pboff = (wn + l15) * 32 + l4 * 8;

  f32x4 acc[4][4];
#pragma unroll
  for (int i = 0; i < 4; i++)
#pragma unroll
    for (int j = 0; j < 4; j++) acc[i][j] = {0.f, 0.f, 0.f, 0.f};

  auto STAGE = [&](int t, int b) {
    u16* da = ldsA + b * 4096 + tid * 8;
    u16* db = ldsB + b * 4096 + tid * 8;
    const int ko = t * 32;
    gl_lds16(aptr0 + ko, da);
    gl_lds16(aptr1 + ko, da + 2048);
    gl_lds16(bptr0 + ko, db);
    gl_lds16(bptr1 + ko, db + 2048);
  };

  auto PHASE = [&](int b) {
    const u16* pa = ldsA + b * 4096 + paoff;
    const u16* pb = ldsB + b * 4096 + pboff;
    bf16x8 av[4], bv[4];
#pragma unroll
    for (int i = 0; i < 4; i++) av[i] = *(const bf16x8*)(pa + i * 512);
#pragma unroll
    for (int j = 0; j < 4; j++) bv[j] = *(const bf16x8*)(pb + j * 512);
#pragma unroll
    for (int i = 0; i < 4; i++)
#pragma unroll
      for (int j = 0; j < 4; j++)
        acc[i][j] = __builtin_amdgcn_mfma_f32_16x16x32_bf16(av[i], bv[j], acc[i][j], 0, 0, 0);
  };

  // double-buffer, counted vmcnt: prefetch of t+1 stays in flight across the barrier
  STAGE(0, 0);
#pragma unroll 2
  for (int t = 0; t < NT - 1; ++t) {
    STAGE(t + 1, (t + 1) & 1);
    wait_bar<4>();            // t's 4 loads landed; t+1's may fly
    PHASE(t & 1);
    bar_only();               // all waves done reading buf t&1 before overwrite
  }
  wait_bar<0>();
  PHASE((NT - 1) & 1);

  // ---------------- epilogue ----------------
  if constexpr (EPI == 1) {
#pragma unroll
    for (int i = 0; i < 4; i++) {
      const int rloc = wm + i * 16 + l4 * 4;
#pragma unroll
      for (int j = 0; j < 4; j++) {
        const int col = n0 + wn + j * 16 + l15;
        const float bias = bias_[e * NTOT + col];
#pragma unroll
        for (int rr = 0; rr < 4; rr++) {
          const int m = m0 + rloc + rr;
          if (m < count) {
            float v = acc[i][j][rr] + bias;
            float g = 0.5f * v * (1.0f + erff(v * 0.70710678118654752f));
            hout[(size_t)(rb + m) * D_DIM + col] = f2bf(g);
          }
        }
      }
    }
  } else {
    const int* lst = list + e * N_TOK;
    const float* wlst = wl + e * N_TOK;
#pragma unroll
    for (int i = 0; i < 4; i++) {
      const int rloc = wm + i * 16 + l4 * 4;
#pragma unroll
      for (int j = 0; j < 4; j++) {
        const int col = n0 + wn + j * 16 + l15;
        const float bias = bias_[e * NTOT + col];
#pragma unroll
        for (int rr = 0; rr < 4; rr++) {
          const int m = m0 + rloc + rr;
          if (m < count) {
            const int tk = lst[m];
            atomicAdd(out + (size_t)tk * C_DIM + col, wlst[m] * (acc[i][j][rr] + bias));
          }
        }
      }
    }
  }
}

extern "C" void kernel_launch(void* const* d_in, const int* in_sizes, int n_in,
                              void* d_out, int out_size, void* d_ws, size_t ws_size,
                              hipStream_t stream) {
  const float* x  = (const float*)d_in[0];
  const float* rw = (const float*)d_in[1];
  const float* W1 = (const float*)d_in[2];
  const float* b1 = (const float*)d_in[3];
  const float* W2 = (const float*)d_in[4];
  const float* b2 = (const float*)d_in[5];
  float* out = (float*)d_out;

  char* ws = (char*)d_ws;
  u16* W1t    = (u16*)(ws);                      // 50,331,648 B
  u16* Xg     = (u16*)(ws + 50331648);           // 33,554,432 B (overlaid by W2t after gemm1)
  u16* W2t    = (u16*)(ws + 50331648);           // 50,331,648 B (written AFTER gemm1)
  int* cnt    = (int*)(ws + 100663296);          // 256 B
  int* rowbase= (int*)(ws + 100663552);          // 256 B
  int* list   = (int*)(ws + 100663808);          // 262,144 B
  float* wl   = (float*)(ws + 100925952);        // 262,144 B
  int* btab   = (int*)(ws + 101188096);          // 2,048 B
  u16* h      = (u16*)(ws + 101190656);          // 100,663,296 B -> end 201,853,952

  zero_init_kernel<<<(out_size + 255) / 256, 256, 0, stream>>>(out, out_size, cnt);
  router_kernel<<<N_TOK / 4, 256, 0, stream>>>(x, rw, cnt, list, wl);
  prefix_kernel<<<1, 64, 0, stream>>>(cnt, rowbase, btab);
  gather_x_kernel<<<dim3(N_TOK / 4, E_NUM), 256, 0, stream>>>(x, cnt, rowbase, list, Xg);
  // W1 [E][C][D] f32 -> W1t [E][D][C] bf16
  transpose_conv_kernel<C_DIM, D_DIM><<<dim3(D_DIM / 64, C_DIM / 64, E_NUM), 256, 0, stream>>>(W1, W1t);
  gemm_tlp_kernel<24, C_DIM, 1><<<MAXB * 24, 256, 0, stream>>>(
      Xg, W1t, b1, btab, cnt, rowbase, list, wl, h, out);
  // W2 [E][D][C] f32 -> W2t [E][C][D] bf16
  transpose_conv_kernel<D_DIM, C_DIM><<<dim3(C_DIM / 64, D_DIM / 64, E_NUM), 256, 0, stream>>>(W2, W2t);
  gemm_tlp_kernel<8, D_DIM, 2><<<MAXB * 8, 256, 0, stream>>>(
      h, W2t, b2, btab, cnt, rowbase, list, wl, h, out);
}